// Round 1
// baseline (1076.504 us; speedup 1.0000x reference)
//
#include <hip/hip_runtime.h>
#include <hip/hip_bf16.h>

// Problem dims
constexpr int Bn = 64;     // batch
constexpr int Dn = 512;    // embed dim
constexpr int Mn = 1024;   // M
constexpr int Ln = 256;    // L
constexpr int Kn = 30;     // K heads

// ---------------------------------------------------------------------------
// Generic tiled SGEMM: C[M,N] = A[M,K] * B[K,N], all row-major, batched via
// blockIdx.z with element strides. 64x64 tile, BK=16, 256 threads, 4x4/thread.
// Requires N % 64 == 0 and K % 16 == 0 (true for all uses here); M is masked.
// ---------------------------------------------------------------------------
__global__ __launch_bounds__(256) void sgemm_kernel(
    const float* __restrict__ A, const float* __restrict__ B,
    float* __restrict__ Cout, int Mdim, int Ndim, int Kdim,
    long strideA, long strideB, long strideC)
{
    constexpr int BM = 64, BN = 64, BK = 16;
    const int bz = blockIdx.z;
    A    += (long)bz * strideA;
    B    += (long)bz * strideB;
    Cout += (long)bz * strideC;

    __shared__ float As[BK][BM + 1];
    __shared__ float Bs[BK][BN + 1];

    const int tid = threadIdx.x;
    const int tx = tid & 15;      // 0..15 col group
    const int ty = tid >> 4;      // 0..15 row group
    const int row0 = blockIdx.y * BM + ty * 4;
    const int col0 = blockIdx.x * BN + tx * 4;

    float acc[4][4] = {};

    for (int k0 = 0; k0 < Kdim; k0 += BK) {
        // Load A tile (BM x BK), store transposed As[kk][m]
        #pragma unroll
        for (int i = 0; i < 4; i++) {
            int idx = tid + i * 256;         // 0..1023
            int m  = idx >> 4;               // 0..63
            int kk = idx & 15;               // 0..15
            int gm = blockIdx.y * BM + m;
            As[kk][m] = (gm < Mdim) ? A[(long)gm * Kdim + (k0 + kk)] : 0.f;
        }
        // Load B tile (BK x BN)
        #pragma unroll
        for (int i = 0; i < 4; i++) {
            int idx = tid + i * 256;
            int kk = idx >> 6;               // 0..15 across i
            int n  = idx & 63;
            Bs[kk][n] = B[(long)(k0 + kk) * Ndim + (blockIdx.x * BN + n)];
        }
        __syncthreads();
        #pragma unroll
        for (int kk = 0; kk < BK; kk++) {
            float a[4], bb[4];
            #pragma unroll
            for (int i = 0; i < 4; i++) a[i] = As[kk][ty * 4 + i];
            #pragma unroll
            for (int j = 0; j < 4; j++) bb[j] = Bs[kk][tx * 4 + j];
            #pragma unroll
            for (int i = 0; i < 4; i++)
                #pragma unroll
                for (int j = 0; j < 4; j++)
                    acc[i][j] += a[i] * bb[j];
        }
        __syncthreads();
    }

    #pragma unroll
    for (int i = 0; i < 4; i++) {
        int r = row0 + i;
        if (r >= Mdim) continue;
        #pragma unroll
        for (int j = 0; j < 4; j++)
            Cout[(long)r * Ndim + col0 + j] = acc[i][j];
    }
}

// ---------------------------------------------------------------------------
// WqQ[b,k,l] = sum_d W_q[k,d] * Q[b,l,d]   (one wave per (b,l))
// ---------------------------------------------------------------------------
__global__ __launch_bounds__(64) void wqq_kernel(
    const float* __restrict__ Wq, const float* __restrict__ Q,
    float* __restrict__ WqQ)
{
    const int l = blockIdx.x, b = blockIdx.y;
    const int lane = threadIdx.x;
    const float* qrow = Q + ((long)b * Ln + l) * Dn;
    float q[8];
    #pragma unroll
    for (int i = 0; i < 8; i++) q[i] = qrow[lane + i * 64];
    for (int k = 0; k < Kn; k++) {
        const float* wrow = Wq + (long)k * Dn;
        float acc = 0.f;
        #pragma unroll
        for (int i = 0; i < 8; i++) acc += wrow[lane + i * 64] * q[i];
        #pragma unroll
        for (int off = 32; off > 0; off >>= 1) acc += __shfl_down(acc, off, 64);
        if (lane == 0) WqQ[((long)b * Kn + k) * Ln + l] = acc;
    }
}

// ---------------------------------------------------------------------------
// Hv (in place over Tv): Hv = tanh(Tv + WvV)
// ---------------------------------------------------------------------------
__global__ void hv_kernel(float* __restrict__ Tv, const float* __restrict__ WvV, long n)
{
    long i = (long)blockIdx.x * blockDim.x + threadIdx.x;
    if (i < n) Tv[i] = tanhf(Tv[i] + WvV[i]);
}

// ---------------------------------------------------------------------------
// Hq[b,k,l] = tanh(WqQ[b,k,l] + sum_m WvV[b,k,m] * C[b,l,m])  (wave per (b,l))
// ---------------------------------------------------------------------------
__global__ __launch_bounds__(64) void hq_kernel(
    const float* __restrict__ WvV, const float* __restrict__ Cb,
    const float* __restrict__ WqQ, float* __restrict__ Hq)
{
    const int l = blockIdx.x, b = blockIdx.y;
    const int lane = threadIdx.x;
    const float* crow = Cb + ((long)b * Ln + l) * Mn;
    const float* wv = WvV + (long)b * Kn * Mn;
    float c[16];
    #pragma unroll
    for (int i = 0; i < 16; i++) c[i] = crow[lane + i * 64];
    for (int k = 0; k < Kn; k++) {
        const float* wrow = wv + (long)k * Mn;
        float acc = 0.f;
        #pragma unroll
        for (int i = 0; i < 16; i++) acc += wrow[lane + i * 64] * c[i];
        #pragma unroll
        for (int off = 32; off > 0; off >>= 1) acc += __shfl_down(acc, off, 64);
        if (lane == 0) {
            long idx = ((long)b * Kn + k) * Ln + l;
            Hq[idx] = tanhf(WqQ[idx] + acc);
        }
    }
}

// ---------------------------------------------------------------------------
// Softmax over COLS: s[m] = sum_k w[k]*H[b,k,m]; a = softmax(s). One block/batch.
// ---------------------------------------------------------------------------
template <int COLS>
__global__ void softmax_kernel(const float* __restrict__ H,
                               const float* __restrict__ w,
                               float* __restrict__ a)
{
    const int b = blockIdx.x;
    const int m = threadIdx.x;
    const float* Hb = H + (long)b * Kn * COLS;
    float s = 0.f;
    #pragma unroll
    for (int k = 0; k < Kn; k++) s += w[k] * Hb[(long)k * COLS + m];

    __shared__ float red[COLS / 64];
    __shared__ float bcast;
    const int wid = m >> 6, lane = m & 63;

    float v = s;
    #pragma unroll
    for (int off = 32; off > 0; off >>= 1) v = fmaxf(v, __shfl_down(v, off, 64));
    if (lane == 0) red[wid] = v;
    __syncthreads();
    if (m == 0) {
        float mx = red[0];
        for (int i = 1; i < COLS / 64; i++) mx = fmaxf(mx, red[i]);
        bcast = mx;
    }
    __syncthreads();
    const float mx = bcast;
    const float e = expf(s - mx);
    v = e;
    #pragma unroll
    for (int off = 32; off > 0; off >>= 1) v += __shfl_down(v, off, 64);
    if (lane == 0) red[wid] = v;
    __syncthreads();
    if (m == 0) {
        float sm = 0.f;
        for (int i = 0; i < COLS / 64; i++) sm += red[i];
        bcast = sm;
    }
    __syncthreads();
    a[(long)b * COLS + m] = e / bcast;
}

// ---------------------------------------------------------------------------
// v1[b,e] = sum_m a_v[b,m] * V[b,e,m]   (wave per (b,e); V row contiguous in m)
// ---------------------------------------------------------------------------
__global__ __launch_bounds__(64) void poolv_kernel(
    const float* __restrict__ a_v, const float* __restrict__ V,
    float* __restrict__ v1)
{
    const int e = blockIdx.x, b = blockIdx.y;
    const int lane = threadIdx.x;
    const float* vrow = V + ((long)b * Dn + e) * Mn;
    const float* av = a_v + (long)b * Mn;
    float acc = 0.f;
    #pragma unroll
    for (int i = 0; i < 16; i++) acc += vrow[lane + i * 64] * av[lane + i * 64];
    #pragma unroll
    for (int off = 32; off > 0; off >>= 1) acc += __shfl_down(acc, off, 64);
    if (lane == 0) v1[(long)b * Dn + e] = acc;
}

// ---------------------------------------------------------------------------
// q1[b,e] = sum_l a_q[b,l] * Q[b,l,e]   (block per b, thread per e; coalesced)
// ---------------------------------------------------------------------------
__global__ __launch_bounds__(512) void poolq_kernel(
    const float* __restrict__ a_q, const float* __restrict__ Q,
    float* __restrict__ q1)
{
    const int b = blockIdx.x, e = threadIdx.x;
    const float* aq = a_q + (long)b * Ln;
    float acc = 0.f;
    for (int l = 0; l < Ln; l++) acc += aq[l] * Q[((long)b * Ln + l) * Dn + e];
    q1[(long)b * Dn + e] = acc;
}

// ---------------------------------------------------------------------------
// Broadcast: out_v[b,m,e] = v1[b,e]; out_q[b,l,e] = q1[b,e]. float4 stores.
// ---------------------------------------------------------------------------
__global__ void bcast_kernel(const float* __restrict__ v1,
                             const float* __restrict__ q1,
                             float* __restrict__ out)
{
    const long nv4 = (long)Bn * Mn * Dn / 4;   // 8,388,608
    const long nq4 = (long)Bn * Ln * Dn / 4;   // 2,097,152
    long idx = (long)blockIdx.x * blockDim.x + threadIdx.x;
    float4* o4 = (float4*)out;
    if (idx < nv4) {
        long fidx = idx * 4;
        int e4 = (int)(fidx & (Dn - 1));
        long bm = fidx >> 9;                   // / 512
        int b = (int)(bm >> 10);               // / 1024
        o4[idx] = *(const float4*)(v1 + (long)b * Dn + e4);
    } else if (idx < nv4 + nq4) {
        long fidx = (idx - nv4) * 4;
        int e4 = (int)(fidx & (Dn - 1));
        long bl = fidx >> 9;
        int b = (int)(bl >> 8);                // / 256
        o4[idx] = *(const float4*)(q1 + (long)b * Dn + e4);
    }
}

// ---------------------------------------------------------------------------

extern "C" void kernel_launch(void* const* d_in, const int* in_sizes, int n_in,
                              void* d_out, int out_size, void* d_ws, size_t ws_size,
                              hipStream_t stream)
{
    const float* V    = (const float*)d_in[0];  // [B, d, M]
    const float* Q    = (const float*)d_in[1];  // [B, L, d]
    const float* W_b  = (const float*)d_in[2];  // [d, d]
    const float* W_v  = (const float*)d_in[3];  // [K, d]
    const float* W_q  = (const float*)d_in[4];  // [K, d]
    const float* w_hv = (const float*)d_in[5];  // [K, 1]
    const float* w_hq = (const float*)d_in[6];  // [K, 1]
    float* out = (float*)d_out;

    // Workspace carve-up (floats)
    float* ws   = (float*)d_ws;
    float* QWb  = ws;                           // [B*L, d]       8,388,608
    float* Cb   = QWb + (long)Bn * Ln * Dn;     // [B, L, M]     16,777,216
    float* WvV  = Cb  + (long)Bn * Ln * Mn;     // [B, K, M]      1,966,080
    float* WqQ  = WvV + (long)Bn * Kn * Mn;     // [B, K, L]        491,520
    float* Tv   = WqQ + (long)Bn * Kn * Ln;     // [B, K, M] (->Hv) 1,966,080
    float* Hq   = Tv  + (long)Bn * Kn * Mn;     // [B, K, L]        491,520
    float* a_v  = Hq  + (long)Bn * Kn * Ln;     // [B, M]
    float* a_q  = a_v + (long)Bn * Mn;          // [B, L]
    float* v1   = a_q + (long)Bn * Ln;          // [B, d]
    float* q1   = v1  + (long)Bn * Dn;          // [B, d]

    // 1. QWb = Q @ W_b : [16384,512] x [512,512]
    sgemm_kernel<<<dim3(Dn / 64, (Bn * Ln) / 64, 1), 256, 0, stream>>>(
        Q, W_b, QWb, Bn * Ln, Dn, Dn, 0, 0, 0);

    // 2. C[b] = QWb[b] @ V[b] : [256,512] x [512,1024], batched
    sgemm_kernel<<<dim3(Mn / 64, Ln / 64, Bn), 256, 0, stream>>>(
        QWb, V, Cb, Ln, Mn, Dn,
        (long)Ln * Dn, (long)Dn * Mn, (long)Ln * Mn);

    // 3. WvV[b] = W_v @ V[b] : [30,512] x [512,1024], batched (A shared)
    sgemm_kernel<<<dim3(Mn / 64, 1, Bn), 256, 0, stream>>>(
        W_v, V, WvV, Kn, Mn, Dn,
        0, (long)Dn * Mn, (long)Kn * Mn);

    // 4. WqQ[b,k,l]
    wqq_kernel<<<dim3(Ln, Bn), 64, 0, stream>>>(W_q, Q, WqQ);

    // 5. Tv[b] = WqQ[b] @ C[b] : [30,256] x [256,1024], batched
    sgemm_kernel<<<dim3(Mn / 64, 1, Bn), 256, 0, stream>>>(
        WqQ, Cb, Tv, Kn, Mn, Ln,
        (long)Kn * Ln, (long)Ln * Mn, (long)Kn * Mn);

    // 6. Hv = tanh(Tv + WvV)  (in place over Tv)
    {
        long n = (long)Bn * Kn * Mn;
        hv_kernel<<<(int)((n + 255) / 256), 256, 0, stream>>>(Tv, WvV, n);
    }

    // 7. Hq = tanh(WqQ + WvV @ C^T)
    hq_kernel<<<dim3(Ln, Bn), 64, 0, stream>>>(WvV, Cb, WqQ, Hq);

    // 8. softmaxes
    softmax_kernel<Mn><<<Bn, Mn, 0, stream>>>(Tv, w_hv, a_v);
    softmax_kernel<Ln><<<Bn, Ln, 0, stream>>>(Hq, w_hq, a_q);

    // 9. pooling
    poolv_kernel<<<dim3(Dn, Bn), 64, 0, stream>>>(a_v, V, v1);
    poolq_kernel<<<Bn, Dn, 0, stream>>>(a_q, Q, q1);

    // 10. broadcast outputs
    {
        long n4 = (long)Bn * Mn * Dn / 4 + (long)Bn * Ln * Dn / 4;
        bcast_kernel<<<(int)((n4 + 255) / 256), 256, 0, stream>>>(v1, q1, out);
    }
}

// Round 4
// 759.758 us; speedup vs baseline: 1.4169x; 1.4169x over previous
//
#include <hip/hip_runtime.h>
#include <hip/hip_bf16.h>

// Problem dims
constexpr int Bn = 64;     // batch
constexpr int Dn = 512;    // embed dim
constexpr int Mn = 1024;   // M
constexpr int Ln = 256;    // L
constexpr int Kn = 30;     // K heads

typedef __bf16 bf16;
typedef __attribute__((ext_vector_type(8))) __bf16 bf16x8;
typedef __attribute__((ext_vector_type(4))) __bf16 bf16x4;
typedef __attribute__((ext_vector_type(4))) float f32x4;

// async global->LDS, 16B per lane; LDS dest is wave-uniform base + lane*16
#define GLL(gp, lp) __builtin_amdgcn_global_load_lds( \
    (const __attribute__((address_space(1))) unsigned int*)(gp), \
    (__attribute__((address_space(3))) unsigned int*)(lp), 16, 0, 0)

struct bf16pair { bf16 h, l; };
__device__ __forceinline__ bf16pair split_f32(float x) {
    bf16pair p;
    p.h = (bf16)x;
    p.l = (bf16)(x - (float)p.h);
    return p;
}

// ---------------------------------------------------------------------------
// bf16x3 split-precision MFMA NT GEMM:
//   C[M,N] = (Ah+Al)[M,K] * (Bh+Bl)[N,K]^T  via  AhBh + AlBh + AhBl
// All operands row-major bf16, row stride Kdim. 128x128 tile, BK=32,
// 256 threads (4 waves 2x2), wave does 64x64 via 4x4 of 16x16x32 MFMAs.
// M,N % 128 == 0, K % 32 == 0. OUT_SPLIT: emit h/l bf16 pair, else fp32.
// ---------------------------------------------------------------------------
template <bool OUT_SPLIT>
__global__ __launch_bounds__(256) void mfma_gemm_nt3(
    const bf16* __restrict__ Ah, const bf16* __restrict__ Al,
    const bf16* __restrict__ Bh, const bf16* __restrict__ Bl,
    float* __restrict__ Cf, bf16* __restrict__ Ch, bf16* __restrict__ Cl,
    int Ndim, int Kdim, long sA, long sB, long sC)
{
    constexpr int BM = 128, BN = 128, BK = 32;
    __shared__ __align__(16) bf16 Ash[BM][BK];   // 8 KB each
    __shared__ __align__(16) bf16 Asl[BM][BK];
    __shared__ __align__(16) bf16 Bsh[BN][BK];
    __shared__ __align__(16) bf16 Bsl[BN][BK];

    const long zA = (long)blockIdx.z * sA;
    const long zB = (long)blockIdx.z * sB;

    const int tid  = threadIdx.x;
    const int w    = tid >> 6;
    const int lane = tid & 63;
    const int wm   = w >> 1, wn = w & 1;
    const int m0 = blockIdx.y * BM, n0 = blockIdx.x * BN;

    // staging: thread t copies 16B = 8 bf16; row t/4 (+64 second pass)
    const int rowt = tid >> 2;
    const int koff = (tid & 3) * 8;
    const bf16* gAh = Ah + zA + (long)(m0 + rowt) * Kdim + koff;
    const bf16* gAl = Al + zA + (long)(m0 + rowt) * Kdim + koff;
    const bf16* gBh = Bh + zB + (long)(n0 + rowt) * Kdim + koff;
    const bf16* gBl = Bl + zB + (long)(n0 + rowt) * Kdim + koff;
    bf16* lAh0 = &Ash[0][0] + w * 512;  bf16* lAh1 = lAh0 + 2048;
    bf16* lAl0 = &Asl[0][0] + w * 512;  bf16* lAl1 = lAl0 + 2048;
    bf16* lBh0 = &Bsh[0][0] + w * 512;  bf16* lBh1 = lBh0 + 2048;
    bf16* lBl0 = &Bsl[0][0] + w * 512;  bf16* lBl1 = lBl0 + 2048;
    const long rstep = (long)64 * Kdim;

    f32x4 acc[4][4];
    const f32x4 zero = {0.f, 0.f, 0.f, 0.f};
    #pragma unroll
    for (int i = 0; i < 4; i++)
        #pragma unroll
        for (int j = 0; j < 4; j++) acc[i][j] = zero;

    const int fr = lane & 15;          // row/col within 16
    const int fk = (lane >> 4) * 8;    // k offset of fragment

    for (int k0 = 0; k0 < Kdim; k0 += BK) {
        GLL(gAh + k0, lAh0); GLL(gAh + rstep + k0, lAh1);
        GLL(gAl + k0, lAl0); GLL(gAl + rstep + k0, lAl1);
        GLL(gBh + k0, lBh0); GLL(gBh + rstep + k0, lBh1);
        GLL(gBl + k0, lBl0); GLL(gBl + rstep + k0, lBl1);
        __syncthreads();               // vmcnt(0) drain + barrier

        bf16x8 ah[4], al[4];
        #pragma unroll
        for (int i = 0; i < 4; i++) {
            ah[i] = *(const bf16x8*)&Ash[wm * 64 + i * 16 + fr][fk];
            al[i] = *(const bf16x8*)&Asl[wm * 64 + i * 16 + fr][fk];
        }
        #pragma unroll
        for (int j = 0; j < 4; j++) {
            bf16x8 bh = *(const bf16x8*)&Bsh[wn * 64 + j * 16 + fr][fk];
            bf16x8 bl = *(const bf16x8*)&Bsl[wn * 64 + j * 16 + fr][fk];
            #pragma unroll
            for (int i = 0; i < 4; i++) {
                acc[i][j] = __builtin_amdgcn_mfma_f32_16x16x32_bf16(ah[i], bh, acc[i][j], 0, 0, 0);
                acc[i][j] = __builtin_amdgcn_mfma_f32_16x16x32_bf16(al[i], bh, acc[i][j], 0, 0, 0);
                acc[i][j] = __builtin_amdgcn_mfma_f32_16x16x32_bf16(ah[i], bl, acc[i][j], 0, 0, 0);
            }
        }
        __syncthreads();
    }

    // epilogue: within 16x16 tile, row = (lane>>4)*4 + r, col = lane&15
    #pragma unroll
    for (int i = 0; i < 4; i++) {
        #pragma unroll
        for (int j = 0; j < 4; j++) {
            #pragma unroll
            for (int r = 0; r < 4; r++) {
                int row = m0 + wm * 64 + i * 16 + (lane >> 4) * 4 + r;
                int col = n0 + wn * 64 + j * 16 + (lane & 15);
                long idx = (long)blockIdx.z * sC + (long)row * Ndim + col;
                float x = acc[i][j][r];
                if (OUT_SPLIT) {
                    bf16pair p = split_f32(x);
                    Ch[idx] = p.h; Cl[idx] = p.l;
                } else {
                    Cf[idx] = x;
                }
            }
        }
    }
}

// ---------------------------------------------------------------------------
// elementwise fp32 -> (hi, lo) bf16 pair (n % 4 == 0)
// ---------------------------------------------------------------------------
__global__ void convert_split_kernel(const float* __restrict__ x,
                                     bf16* __restrict__ yh, bf16* __restrict__ yl,
                                     long n)
{
    long i = ((long)blockIdx.x * blockDim.x + threadIdx.x) * 4;
    if (i < n) {
        float4 v = *(const float4*)(x + i);
        bf16pair p0 = split_f32(v.x), p1 = split_f32(v.y);
        bf16pair p2 = split_f32(v.z), p3 = split_f32(v.w);
        bf16x4 h = {p0.h, p1.h, p2.h, p3.h};
        bf16x4 l = {p0.l, p1.l, p2.l, p3.l};
        *(bf16x4*)(yh + i) = h;
        *(bf16x4*)(yl + i) = l;
    }
}

// ---------------------------------------------------------------------------
// transpose + split: Xt{h,l}[c][r] = split(X[r][c]). X:[R,C] fp32, %32==0.
// block (32,8), grid (C/32, R/32, batches)
// ---------------------------------------------------------------------------
__global__ void transpose_split_kernel(const float* __restrict__ X,
                                       bf16* __restrict__ Xth, bf16* __restrict__ Xtl,
                                       int R, int C, long sX, long sXt)
{
    __shared__ float tile[32][33];
    const float* Xb = X + (long)blockIdx.z * sX;
    bf16* Xh = Xth + (long)blockIdx.z * sXt;
    bf16* Xl = Xtl + (long)blockIdx.z * sXt;
    const int c0 = blockIdx.x * 32, r0 = blockIdx.y * 32;
    const int tx = threadIdx.x, ty = threadIdx.y;
    #pragma unroll
    for (int i = 0; i < 4; i++)
        tile[ty + 8 * i][tx] = Xb[(long)(r0 + ty + 8 * i) * C + c0 + tx];
    __syncthreads();
    #pragma unroll
    for (int i = 0; i < 4; i++) {
        float v = tile[tx][ty + 8 * i];
        bf16pair p = split_f32(v);
        long o = (long)(c0 + ty + 8 * i) * R + r0 + tx;
        Xh[o] = p.h; Xl[o] = p.l;
    }
}

// ---------------------------------------------------------------------------
// fp32 tiled SGEMM (thin ops): C[M,N] = A[M,K]*B[K,N]
// ---------------------------------------------------------------------------
__global__ __launch_bounds__(256) void sgemm_kernel(
    const float* __restrict__ A, const float* __restrict__ B,
    float* __restrict__ Cout, int Mdim, int Ndim, int Kdim,
    long strideA, long strideB, long strideC)
{
    constexpr int BM = 64, BN = 64, BK = 16;
    const int bz = blockIdx.z;
    A    += (long)bz * strideA;
    B    += (long)bz * strideB;
    Cout += (long)bz * strideC;

    __shared__ float As[BK][BM + 1];
    __shared__ float Bs[BK][BN + 1];

    const int tid = threadIdx.x;
    const int tx = tid & 15;
    const int ty = tid >> 4;
    const int row0 = blockIdx.y * BM + ty * 4;
    const int col0 = blockIdx.x * BN + tx * 4;

    float acc[4][4] = {};

    for (int k0 = 0; k0 < Kdim; k0 += BK) {
        #pragma unroll
        for (int i = 0; i < 4; i++) {
            int idx = tid + i * 256;
            int m  = idx >> 4;
            int kk = idx & 15;
            int gm = blockIdx.y * BM + m;
            As[kk][m] = (gm < Mdim) ? A[(long)gm * Kdim + (k0 + kk)] : 0.f;
        }
        #pragma unroll
        for (int i = 0; i < 4; i++) {
            int idx = tid + i * 256;
            int kk = idx >> 6;
            int n  = idx & 63;
            Bs[kk][n] = B[(long)(k0 + kk) * Ndim + (blockIdx.x * BN + n)];
        }
        __syncthreads();
        #pragma unroll
        for (int kk = 0; kk < BK; kk++) {
            float a[4], bb[4];
            #pragma unroll
            for (int i = 0; i < 4; i++) a[i] = As[kk][ty * 4 + i];
            #pragma unroll
            for (int j = 0; j < 4; j++) bb[j] = Bs[kk][tx * 4 + j];
            #pragma unroll
            for (int i = 0; i < 4; i++)
                #pragma unroll
                for (int j = 0; j < 4; j++)
                    acc[i][j] += a[i] * bb[j];
        }
        __syncthreads();
    }

    #pragma unroll
    for (int i = 0; i < 4; i++) {
        int r = row0 + i;
        if (r >= Mdim) continue;
        #pragma unroll
        for (int j = 0; j < 4; j++)
            Cout[(long)r * Ndim + col0 + j] = acc[i][j];
    }
}

// ---------------------------------------------------------------------------
// WqQ[b,k,l] = sum_d W_q[k,d] * Q[b,l,d]   (one wave per (b,l))
// ---------------------------------------------------------------------------
__global__ __launch_bounds__(64) void wqq_kernel(
    const float* __restrict__ Wq, const float* __restrict__ Q,
    float* __restrict__ WqQ)
{
    const int l = blockIdx.x, b = blockIdx.y;
    const int lane = threadIdx.x;
    const float* qrow = Q + ((long)b * Ln + l) * Dn;
    float q[8];
    #pragma unroll
    for (int i = 0; i < 8; i++) q[i] = qrow[lane + i * 64];
    for (int k = 0; k < Kn; k++) {
        const float* wrow = Wq + (long)k * Dn;
        float acc = 0.f;
        #pragma unroll
        for (int i = 0; i < 8; i++) acc += wrow[lane + i * 64] * q[i];
        #pragma unroll
        for (int off = 32; off > 0; off >>= 1) acc += __shfl_down(acc, off, 64);
        if (lane == 0) WqQ[((long)b * Kn + k) * Ln + l] = acc;
    }
}

__global__ void hv_kernel(float* __restrict__ Tv, const float* __restrict__ WvV, long n)
{
    long i = (long)blockIdx.x * blockDim.x + threadIdx.x;
    if (i < n) Tv[i] = tanhf(Tv[i] + WvV[i]);
}

// ---------------------------------------------------------------------------
// Hq[b,k,l] = tanh(WqQ[b,k,l] + sum_m WvV[b,k,m] * C[b,l,m])  (wave per (b,l))
// ---------------------------------------------------------------------------
__global__ __launch_bounds__(64) void hq_kernel(
    const float* __restrict__ WvV, const float* __restrict__ Cb,
    const float* __restrict__ WqQ, float* __restrict__ Hq)
{
    const int l = blockIdx.x, b = blockIdx.y;
    const int lane = threadIdx.x;
    const float* crow = Cb + ((long)b * Ln + l) * Mn;
    const float* wv = WvV + (long)b * Kn * Mn;
    float c[16];
    #pragma unroll
    for (int i = 0; i < 16; i++) c[i] = crow[lane + i * 64];
    for (int k = 0; k < Kn; k++) {
        const float* wrow = wv + (long)k * Mn;
        float acc = 0.f;
        #pragma unroll
        for (int i = 0; i < 16; i++) acc += wrow[lane + i * 64] * c[i];
        #pragma unroll
        for (int off = 32; off > 0; off >>= 1) acc += __shfl_down(acc, off, 64);
        if (lane == 0) {
            long idx = ((long)b * Kn + k) * Ln + l;
            Hq[idx] = tanhf(WqQ[idx] + acc);
        }
    }
}

template <int COLS>
__global__ void softmax_kernel(const float* __restrict__ H,
                               const float* __restrict__ w,
                               float* __restrict__ a)
{
    const int b = blockIdx.x;
    const int m = threadIdx.x;
    const float* Hb = H + (long)b * Kn * COLS;
    float s = 0.f;
    #pragma unroll
    for (int k = 0; k < Kn; k++) s += w[k] * Hb[(long)k * COLS + m];

    __shared__ float red[COLS / 64];
    __shared__ float bcast;
    const int wid = m >> 6, lane = m & 63;

    float v = s;
    #pragma unroll
    for (int off = 32; off > 0; off >>= 1) v = fmaxf(v, __shfl_down(v, off, 64));
    if (lane == 0) red[wid] = v;
    __syncthreads();
    if (m == 0) {
        float mx = red[0];
        for (int i = 1; i < COLS / 64; i++) mx = fmaxf(mx, red[i]);
        bcast = mx;
    }
    __syncthreads();
    const float mx = bcast;
    const float e = expf(s - mx);
    v = e;
    #pragma unroll
    for (int off = 32; off > 0; off >>= 1) v += __shfl_down(v, off, 64);
    if (lane == 0) red[wid] = v;
    __syncthreads();
    if (m == 0) {
        float sm = 0.f;
        for (int i = 0; i < COLS / 64; i++) sm += red[i];
        bcast = sm;
    }
    __syncthreads();
    a[(long)b * COLS + m] = e / bcast;
}

__global__ __launch_bounds__(64) void poolv_kernel(
    const float* __restrict__ a_v, const float* __restrict__ V,
    float* __restrict__ v1)
{
    const int e = blockIdx.x, b = blockIdx.y;
    const int lane = threadIdx.x;
    const float* vrow = V + ((long)b * Dn + e) * Mn;
    const float* av = a_v + (long)b * Mn;
    float acc = 0.f;
    #pragma unroll
    for (int i = 0; i < 16; i++) acc += vrow[lane + i * 64] * av[lane + i * 64];
    #pragma unroll
    for (int off = 32; off > 0; off >>= 1) acc += __shfl_down(acc, off, 64);
    if (lane == 0) v1[(long)b * Dn + e] = acc;
}

__global__ __launch_bounds__(512) void poolq_kernel(
    const float* __restrict__ a_q, const float* __restrict__ Q,
    float* __restrict__ q1)
{
    const int b = blockIdx.x, e = threadIdx.x;
    const float* aq = a_q + (long)b * Ln;
    float acc = 0.f;
    for (int l = 0; l < Ln; l++) acc += aq[l] * Q[((long)b * Ln + l) * Dn + e];
    q1[(long)b * Dn + e] = acc;
}

__global__ void bcast_kernel(const float* __restrict__ v1,
                             const float* __restrict__ q1,
                             float* __restrict__ out)
{
    const long nv4 = (long)Bn * Mn * Dn / 4;
    const long nq4 = (long)Bn * Ln * Dn / 4;
    long idx = (long)blockIdx.x * blockDim.x + threadIdx.x;
    float4* o4 = (float4*)out;
    if (idx < nv4) {
        long fidx = idx * 4;
        int e4 = (int)(fidx & (Dn - 1));
        long bm = fidx >> 9;
        int b = (int)(bm >> 10);
        o4[idx] = *(const float4*)(v1 + (long)b * Dn + e4);
    } else if (idx < nv4 + nq4) {
        long fidx = (idx - nv4) * 4;
        int e4 = (int)(fidx & (Dn - 1));
        long bl = fidx >> 9;
        int b = (int)(bl >> 8);
        o4[idx] = *(const float4*)(q1 + (long)b * Dn + e4);
    }
}

// ---------------------------------------------------------------------------

extern "C" void kernel_launch(void* const* d_in, const int* in_sizes, int n_in,
                              void* d_out, int out_size, void* d_ws, size_t ws_size,
                              hipStream_t stream)
{
    const float* V    = (const float*)d_in[0];  // [B, d, M]
    const float* Q    = (const float*)d_in[1];  // [B, L, d]
    const float* W_b  = (const float*)d_in[2];  // [d, d]
    const float* W_v  = (const float*)d_in[3];  // [K, d]
    const float* W_q  = (const float*)d_in[4];  // [K, d]
    const float* w_hv = (const float*)d_in[5];  // [K, 1]
    const float* w_hq = (const float*)d_in[6];  // [K, 1]
    float* out = (float*)d_out;

    constexpr int Bh2 = Bn / 2;                  // half-batch = 32
    const long vtHalf = (long)Bh2 * Mn * Dn;     // 16,777,216 elems

    // Workspace carve-up (peak ~188 MB)
    bf16* Vth  = (bf16*)d_ws;                    // half-batch V^T hi
    bf16* Vtl  = Vth + vtHalf;                   // half-batch V^T lo
    bf16* QWbh = Vtl + vtHalf;                   // [B*L, d] hi
    bf16* QWbl = QWbh + (long)Bn * Ln * Dn;      // [B*L, d] lo
    float* Cb  = (float*)(QWbl + (long)Bn * Ln * Dn); // [B,L,M] fp32, 67 MB
    // Qh/Ql/Wbt pairs are dead before Cb is first written (GEMM1 < GEMM2):
    bf16* Qh   = (bf16*)Cb;
    bf16* Ql   = Qh + (long)Bn * Ln * Dn;
    bf16* Wbth = Ql + (long)Bn * Ln * Dn;
    bf16* Wbtl = Wbth + (long)Dn * Dn;
    float* WvV = Cb  + (long)Bn * Ln * Mn;       // [B,K,M]
    float* WqQ = WvV + (long)Bn * Kn * Mn;       // [B,K,L]
    float* Tv  = WqQ + (long)Bn * Kn * Ln;       // [B,K,M] (->Hv)
    float* Hq  = Tv  + (long)Bn * Kn * Mn;       // [B,K,L]
    float* a_v = Hq  + (long)Bn * Kn * Ln;
    float* a_q = a_v + (long)Bn * Mn;
    float* v1  = a_q + (long)Bn * Ln;
    float* q1  = v1  + (long)Bn * Dn;

    // 0a. Q -> (Qh, Ql)
    {
        long n = (long)Bn * Ln * Dn;
        convert_split_kernel<<<(int)(n / 4 + 255) / 256, 256, 0, stream>>>(Q, Qh, Ql, n);
    }
    // 0b. W_b -> Wbt hi/lo (transposed)
    transpose_split_kernel<<<dim3(Dn / 32, Dn / 32, 1), dim3(32, 8), 0, stream>>>(
        W_b, Wbth, Wbtl, Dn, Dn, 0, 0);

    // 1. QWb = Q @ W_b  (bf16x3, split output): [16384,512] x [512,512]
    mfma_gemm_nt3<true><<<dim3(Dn / 128, (Bn * Ln) / 128, 1), 256, 0, stream>>>(
        Qh, Ql, Wbth, Wbtl, nullptr, QWbh, QWbl, Dn, Dn, 0, 0, 0);

    // 2. C[b] = QWb[b] @ V[b] in two half-batches (Vt buffer reused; stream
    //    order serializes transpose/GEMM pairs).
    for (int h = 0; h < 2; h++) {
        const float* Vh = V + (long)h * Bh2 * Dn * Mn;
        transpose_split_kernel<<<dim3(Mn / 32, Dn / 32, Bh2), dim3(32, 8), 0, stream>>>(
            Vh, Vth, Vtl, Dn, Mn, (long)Dn * Mn, (long)Mn * Dn);
        mfma_gemm_nt3<false><<<dim3(Mn / 128, Ln / 128, Bh2), 256, 0, stream>>>(
            QWbh + (long)h * Bh2 * Ln * Dn, QWbl + (long)h * Bh2 * Ln * Dn,
            Vth, Vtl,
            Cb + (long)h * Bh2 * Ln * Mn, nullptr, nullptr,
            Mn, Dn, (long)Ln * Dn, (long)Mn * Dn, (long)Ln * Mn);
    }

    // 3. WvV[b] = W_v @ V[b] : fp32, batched (A shared)
    sgemm_kernel<<<dim3(Mn / 64, 1, Bn), 256, 0, stream>>>(
        W_v, V, WvV, Kn, Mn, Dn,
        0, (long)Dn * Mn, (long)Kn * Mn);

    // 4. WqQ[b,k,l]
    wqq_kernel<<<dim3(Ln, Bn), 64, 0, stream>>>(W_q, Q, WqQ);

    // 5. Tv[b] = WqQ[b] @ C[b] : fp32, batched
    sgemm_kernel<<<dim3(Mn / 64, 1, Bn), 256, 0, stream>>>(
        WqQ, Cb, Tv, Kn, Mn, Ln,
        (long)Kn * Ln, (long)Ln * Mn, (long)Kn * Mn);

    // 6. Hv = tanh(Tv + WvV)  (in place over Tv)
    {
        long n = (long)Bn * Kn * Mn;
        hv_kernel<<<(int)((n + 255) / 256), 256, 0, stream>>>(Tv, WvV, n);
    }

    // 7. Hq = tanh(WqQ + WvV @ C^T)
    hq_kernel<<<dim3(Ln, Bn), 64, 0, stream>>>(WvV, Cb, WqQ, Hq);

    // 8. softmaxes
    softmax_kernel<Mn><<<Bn, Mn, 0, stream>>>(Tv, w_hv, a_v);
    softmax_kernel<Ln><<<Bn, Ln, 0, stream>>>(Hq, w_hq, a_q);

    // 9. pooling
    poolv_kernel<<<dim3(Dn, Bn), 64, 0, stream>>>(a_v, V, v1);
    poolq_kernel<<<Bn, Dn, 0, stream>>>(a_q, Q, q1);

    // 10. broadcast outputs
    {
        long n4 = (long)Bn * Mn * Dn / 4 + (long)Bn * Ln * Dn / 4;
        bcast_kernel<<<(int)((n4 + 255) / 256), 256, 0, stream>>>(v1, q1, out);
    }
}